// Round 17
// baseline (79.519 us; speedup 1.0000x reference)
//
#include <hip/hip_runtime.h>

#define BB 64
#define CC 3
#define HH 224
#define WW 224
#define KK 37
#define PP 18
#define PLANE (HH*WW)

#define BM 32             // output rows per block; 224 = 7*32
#define BROWS 68          // BM + KK - 1
#define BSTR 264          // shorts; conflict-free; rows 16B-aligned
#define FRAGS 2560        // shorts per (slab,ky): 5q x 2hi x 32ln x 8j
#define NTT (8*CC*KK)     // 888 fragment blocks
#define TT_BYTES ((size_t)NTT * FRAGS * sizeof(unsigned short))  // ~4.55 MB
#define NBLK 1344         // 7 ybands x 192 planes; 1344 = 8 x 168

typedef __attribute__((ext_vector_type(8)))  __bf16 bf16x8;
typedef __attribute__((ext_vector_type(4)))  unsigned int u32x4;
typedef __attribute__((ext_vector_type(16))) float f32x16;

__device__ __forceinline__ unsigned short f2bf(float f) {
    unsigned int u = __float_as_uint(f);
    return (unsigned short)((u + 0x7FFFu + ((u >> 16) & 1u)) >> 16);   // RNE
}
__device__ __forceinline__ float bf2f(unsigned short h) {
    return __uint_as_float(((unsigned int)h) << 16);
}

// frag[s][q][hi][ln][j] = w[ky][16q+8hi+j - ln] (0 outside band); + targets
__global__ __launch_bounds__(256) void build_frags(
    const float* __restrict__ psf, unsigned short* __restrict__ tt,
    const int* __restrict__ targets, float* __restrict__ tout)
{
    const int s = blockIdx.x;                // (p*3+c)*37 + ky
    const int ky = s % KK;
    const int pc = s / KK;
    const int p = pc / CC, c = pc - (pc / CC) * CC;
    const float* wrow = psf + (size_t)(((p*5 + 2)*CC + c)*KK + ky) * KK;
    unsigned short* dst = tt + (size_t)s * FRAGS;
    for (int e = threadIdx.x; e < FRAGS; e += 256) {
        int j = e & 7, ln = (e >> 3) & 31, hi = (e >> 8) & 1, q = e >> 9;
        int kx = 16*q + 8*hi + j - ln;
        dst[e] = (kx >= 0 && kx < KK) ? f2bf(wrow[kx]) : (unsigned short)0;
    }
    if (s == 0 && threadIdx.x < BB) tout[threadIdx.x] = (float)targets[threadIdx.x];
}

// 5 asm global loads; completion via hand-counted vmcnt (R12/R13-proven)
__device__ __forceinline__ void load_bq_asm(u32x4 (&bq)[5], const unsigned short* kybase) {
    const unsigned short* p = kybase + 1024;   // center; q*1024B-2048 fits 13-bit imm
    asm volatile("global_load_dwordx4 %0, %1, off offset:-2048" : "=v"(bq[0]) : "v"(p));
    asm volatile("global_load_dwordx4 %0, %1, off offset:-1024" : "=v"(bq[1]) : "v"(p));
    asm volatile("global_load_dwordx4 %0, %1, off"              : "=v"(bq[2]) : "v"(p));
    asm volatile("global_load_dwordx4 %0, %1, off offset:1024"  : "=v"(bq[3]) : "v"(p));
    asm volatile("global_load_dwordx4 %0, %1, off offset:2048"  : "=v"(bq[4]) : "v"(p));
}

// Burst of ds_read_b128 (R16-validated asm form); completion via counted lgkmcnt.
template<int NC>
__device__ __forceinline__ void ds_burst(u32x4 (&af)[NC], const unsigned short* rp) {
    unsigned a = (unsigned)(uintptr_t)rp;
    asm volatile("ds_read_b128 %0, %1 offset:0"   : "=v"(af[0]) : "v"(a));
    asm volatile("ds_read_b128 %0, %1 offset:32"  : "=v"(af[1]) : "v"(a));
    asm volatile("ds_read_b128 %0, %1 offset:64"  : "=v"(af[2]) : "v"(a));
    asm volatile("ds_read_b128 %0, %1 offset:96"  : "=v"(af[3]) : "v"(a));
    asm volatile("ds_read_b128 %0, %1 offset:128" : "=v"(af[4]) : "v"(a));
    if constexpr (NC > 5) {
        asm volatile("ds_read_b128 %0, %1 offset:160" : "=v"(af[5]) : "v"(a));
        asm volatile("ds_read_b128 %0, %1 offset:192" : "=v"(af[6]) : "v"(a));
    }
}

// counted wait on BOTH pipes + scheduler fence (rule #18).
// DS completes in order: lgkmcnt(NC) -> the older burst's NC reads done.
template<int NC>
__device__ __forceinline__ void wait_both() {
    if constexpr (NC == 7)
        asm volatile("s_waitcnt vmcnt(5) lgkmcnt(7)" ::: "memory");
    else
        asm volatile("s_waitcnt vmcnt(5) lgkmcnt(5)" ::: "memory");
    __builtin_amdgcn_sched_barrier(0);
}

#define MFMA_(T,AF,Q) T = __builtin_amdgcn_mfma_f32_32x32x16_bf16( \
    __builtin_bit_cast(bf16x8, af[AF]), __builtin_bit_cast(bf16x8, bq[Q]), T, 0, 0, 0)

// Pure-MFMA cluster, operands fully in regs. NT=2: tiles +0,+32; NT=1: +0.
template<int NT, int NC>
__device__ __forceinline__ void cluster(const u32x4 (&af)[NC], const u32x4 (&bq)[5],
                                        f32x16& A0, f32x16& A1)
{
    if constexpr (NT == 2) {
        MFMA_(A0,0,0);
        MFMA_(A0,1,1);
        MFMA_(A0,2,2); MFMA_(A1,2,0);
        MFMA_(A0,3,3); MFMA_(A1,3,1);
        MFMA_(A0,4,4); MFMA_(A1,4,2);
        MFMA_(A1,5,3);
        MFMA_(A1,6,4);
    } else {
        MFMA_(A0,0,0);
        MFMA_(A0,1,1);
        MFMA_(A0,2,2);
        MFMA_(A0,3,3);
        MFMA_(A0,4,4);
    }
}

#define SP1 __builtin_amdgcn_s_setprio(1)
#define SP0 __builtin_amdgcn_s_setprio(0)

// Full 2-deep dual pipeline: af (ds, counted lgkmcnt) AND bq (global, counted
// vmcnt) for ky+2 issued right after cluster(ky) -> each load covered by a full
// phase (~400cy). Max in flight: 14 ds (<=15 HW counter), 10 vm. Live regs:
// af 56 + bq 40 + acc 32 + addr ~15 = ~143 <= 170 @ (256,3) -> no spill.
template<int NT>
__device__ __forceinline__ void kloop_ws(
    const unsigned short* base,              // &s_band[ln*BSTR + 64w + 8hi]
    const unsigned short* fb,                // tt frag base incl. lane offset
    f32x16& A0, f32x16& A1)
{
    constexpr int NC = (NT == 2) ? 7 : 5;
    u32x4 afA[NC], afB[NC], bqA[5], bqB[5];
    ds_burst<NC>(afA, base);                 // ky 0
    load_bq_asm(bqA, fb);
    ds_burst<NC>(afB, base + BSTR);          // ky 1
    load_bq_asm(bqB, fb + FRAGS);
    for (int ky = 0; ky < KK - 2; ky += 2) {
        wait_both<NC>();                     // afA+bqA(ky) done; B-set in flight
        SP1; cluster<NT, NC>(afA, bqA, A0, A1); SP0;
        ds_burst<NC>(afA, base + (ky + 2)*BSTR);
        load_bq_asm(bqA, fb + (size_t)(ky + 2)*FRAGS);
        wait_both<NC>();                     // afB+bqB(ky+1) done; A-set in flight
        SP1; cluster<NT, NC>(afB, bqB, A0, A1); SP0;
        if (ky + 3 < KK) {
            ds_burst<NC>(afB, base + (ky + 3)*BSTR);
            load_bq_asm(bqB, fb + (size_t)(ky + 3)*FRAGS);
        }
    }
    asm volatile("s_waitcnt vmcnt(0) lgkmcnt(0)" ::: "memory");
    __builtin_amdgcn_sched_barrier(0);
    SP1; cluster<NT, NC>(afA, bqA, A0, A1); SP0;   // ky = 36
}

// Fallback (tiny ws): R12's unpipelined path.
__device__ __forceinline__ void load_bq_fb(u32x4 (&bq)[5], const unsigned short* s_w16,
                                           int ky, int hi, int ln) {
    #pragma unroll
    for (int q = 0; q < 5; ++q) {
        union { u32x4 v; unsigned short s[8]; } u;
        #pragma unroll
        for (int j = 0; j < 8; ++j) {
            int kx = 16*q + 8*hi + j - ln;
            u.s[j] = (kx >= 0 && kx < KK) ? s_w16[ky*40 + kx] : (unsigned short)0;
        }
        bq[q] = u.v;
    }
}

template<int NT, int NC>
__device__ __forceinline__ void kloop_fb(
    const unsigned short* base, const unsigned short* s_w16,
    int hi, int ln, f32x16& A0, f32x16& A1)
{
    u32x4 af[NC], bq[5];
    for (int ky = 0; ky < KK; ++ky) {
        load_bq_fb(bq, s_w16, ky, hi, ln);
        #pragma unroll
        for (int c = 0; c < NC; ++c)
            af[c] = *(const u32x4*)(base + ky*BSTR + 16*c);
        cluster<NT, NC>(af, bq, A0, A1);
    }
}

template<bool FROM_WS>
__global__ __launch_bounds__(256, 3) void optics_mfma(
    const float* __restrict__ batch,
    const float* __restrict__ psf,
    const unsigned short* __restrict__ tt,
    const int* __restrict__ params,
    const float* __restrict__ weights,
    float* __restrict__ out)
{
    __shared__ __align__(16) unsigned short s_band[BROWS*BSTR + 16]; // 35,936 B
    __shared__ __align__(16) unsigned short s_w16[FROM_WS ? 8 : KK*40];

    const int tid = threadIdx.x;
    // XCD-chunked bijective swizzle: XCD j gets 168 consecutive items = 24 planes
    const int n = blockIdx.x;                 // 0..1343
    const int item = (n & 7) * (NBLK / 8) + (n >> 3);
    const int plane = item / 7;               // 0..191 (consecutive items share tt)
    const int yband = item - plane*7;         // 0..6
    const int b = plane / CC, c = plane - b*CC;
    const int y0 = yband * BM;
    const int p = params[b];

    // --- stage reflect-padded band, fp32 -> bf16 ---
    const float* src = batch + (size_t)plane * PLANE;
    for (int i = tid; i < BROWS*56; i += 256) {
        int r = i / 56, g = i - r*56;
        int gy = y0 + r - PP;
        gy = gy < 0 ? -gy : (gy >= HH ? 2*HH - 2 - gy : gy);
        float4 v = *(const float4*)&src[gy*WW + 4*g];
        unsigned int lo  = f2bf(v.x) | ((unsigned int)f2bf(v.y) << 16);
        unsigned int hi2 = f2bf(v.z) | ((unsigned int)f2bf(v.w) << 16);
        unsigned int* d = (unsigned int*)&s_band[r*BSTR + PP + 4*g];
        d[0] = lo; d[1] = hi2;
    }
    for (int i = tid; i < BROWS*40; i += 256) {
        int r = i / 40, e = i - r*40;
        int col = e < PP ? e : (224 + e);     // e=18..39 -> col 242..263
        unsigned short v = 0;
        if (col < 260) {
            int gy = y0 + r - PP;
            gy = gy < 0 ? -gy : (gy >= HH ? 2*HH - 2 - gy : gy);
            int gx = col - PP;
            gx = gx < 0 ? -gx : (gx >= WW ? 2*WW - 2 - gx : gx);
            v = f2bf(src[gy*WW + gx]);
        }
        s_band[r*BSTR + col] = v;
    }
    if (tid < 16) s_band[BROWS*BSTR + tid] = 0;   // guard tail (tile-6 overrun, B=0)
    if constexpr (!FROM_WS) {
        const float* ksrc = psf + (size_t)((p*5 + 2)*CC + c) * (KK*KK);
        for (int i = tid; i < KK*KK; i += 256) {
            int ky_ = i / KK, kx_ = i - ky_*KK;
            s_w16[ky_*40 + kx_] = f2bf(ksrc[i]);
        }
    }
    __syncthreads();     // drains all counters -> clean base for hand counting

    const int lane = tid & 63;
    const int w    = tid >> 6;               // wave 0..3: tiles {0,1}{2,3}{4,5}{6}
    const int ln   = lane & 31;
    const int hi   = lane >> 5;

    const unsigned short* base = &s_band[ln*BSTR + 64*w + 8*hi];

    f32x16 A0 = {0,0,0,0, 0,0,0,0, 0,0,0,0, 0,0,0,0};
    f32x16 A1 = A0;

    if constexpr (FROM_WS) {
        const unsigned short* fb = tt + (size_t)((p*CC + c)*KK)*FRAGS + hi*256 + ln*8;
        if (w < 3) kloop_ws<2>(base, fb, A0, A1);
        else       kloop_ws<1>(base, fb, A0, A1);
    } else {
        if (w < 3) kloop_fb<2, 7>(base, s_w16, hi, ln, A0, A1);
        else       kloop_fb<1, 5>(base, s_w16, hi, ln, A0, A1);
    }

    // --- epilogue: blend + store (m74 D layout) ---
    const float wt = weights[b];
    const float w1 = 1.0f - wt;
    float* dst = out + (size_t)plane * PLANE;
#define EPI(ACC, GT) { \
    _Pragma("unroll") \
    for (int r = 0; r < 16; ++r) { \
        const int rowL = (r & 3) + 8*(r >> 2) + 4*hi; \
        const int yo = y0 + rowL; \
        const int xo = 32*(GT) + ln; \
        const float orig = bf2f(s_band[(rowL + PP)*BSTR + xo + PP]); \
        dst[yo*WW + xo] = w1*orig + wt*ACC[r]; \
    } }
    EPI(A0, 2*w)
    if (w < 3) EPI(A1, 2*w + 1)
#undef EPI
}

__global__ void copy_targets(const int* __restrict__ t, float* __restrict__ out) {
    int i = threadIdx.x;
    if (i < BB) out[i] = (float)t[i];
}

extern "C" void kernel_launch(void* const* d_in, const int* in_sizes, int n_in,
                              void* d_out, int out_size, void* d_ws, size_t ws_size,
                              hipStream_t stream) {
    const float* batch   = (const float*)d_in[0];
    const int*   targets = (const int*)d_in[1];
    const float* psf     = (const float*)d_in[2];
    const int*   params  = (const int*)d_in[3];
    const float* weights = (const float*)d_in[4];
    float* out = (float*)d_out;
    unsigned short* tt = (unsigned short*)d_ws;

    if (ws_size >= TT_BYTES) {
        build_frags<<<NTT, 256, 0, stream>>>(psf, tt, targets,
                                             out + (size_t)BB*CC*PLANE);
        optics_mfma<true><<<NBLK, 256, 0, stream>>>(batch, psf, tt, params, weights, out);
    } else {
        optics_mfma<false><<<NBLK, 256, 0, stream>>>(batch, psf, tt, params, weights, out);
        copy_targets<<<1, 64, 0, stream>>>(targets, out + (size_t)BB*CC*PLANE);
    }
}

// Round 18
// 72.443 us; speedup vs baseline: 1.0977x; 1.0977x over previous
//
#include <hip/hip_runtime.h>

#define BB 64
#define CC 3
#define HH 224
#define WW 224
#define KK 37
#define PP 18
#define PLANE (HH*WW)

#define BM 64             // output rows per block (2 stripes); 224 = 3*64 + 32
#define BROWS 100         // BM + KK - 1
#define BSTR 264          // shorts per band row
#define FRAGS 2560        // shorts per (slab,ky): 5q x 2hi x 32ln x 8j
#define NTT (8*CC*KK)     // 888 fragment blocks
#define TT_BYTES ((size_t)NTT * FRAGS * sizeof(unsigned short))  // ~4.55 MB
#define NBLK 768          // 4 ybands x 192 planes = 3 per CU exactly

typedef __attribute__((ext_vector_type(8)))  __bf16 bf16x8;
typedef __attribute__((ext_vector_type(4)))  unsigned int u32x4;
typedef __attribute__((ext_vector_type(16))) float f32x16;

__device__ __forceinline__ unsigned short f2bf(float f) {
    unsigned int u = __float_as_uint(f);
    return (unsigned short)((u + 0x7FFFu + ((u >> 16) & 1u)) >> 16);   // RNE
}
__device__ __forceinline__ float bf2f(unsigned short h) {
    return __uint_as_float(((unsigned int)h) << 16);
}

// frag[s][q][hi][ln][j] = w[ky][16q+8hi+j - ln] (0 outside band); + targets
__global__ __launch_bounds__(256) void build_frags(
    const float* __restrict__ psf, unsigned short* __restrict__ tt,
    const int* __restrict__ targets, float* __restrict__ tout)
{
    const int s = blockIdx.x;                // (p*3+c)*37 + ky
    const int ky = s % KK;
    const int pc = s / KK;
    const int p = pc / CC, c = pc - (pc / CC) * CC;
    const float* wrow = psf + (size_t)(((p*5 + 2)*CC + c)*KK + ky) * KK;
    unsigned short* dst = tt + (size_t)s * FRAGS;
    for (int e = threadIdx.x; e < FRAGS; e += 256) {
        int j = e & 7, ln = (e >> 3) & 31, hi = (e >> 8) & 1, q = e >> 9;
        int kx = 16*q + 8*hi + j - ln;
        dst[e] = (kx >= 0 && kx < KK) ? f2bf(wrow[kx]) : (unsigned short)0;
    }
    if (s == 0 && threadIdx.x < BB) tout[threadIdx.x] = (float)targets[threadIdx.x];
}

// 5 asm global loads; completion via hand-counted vmcnt (R12/R13-proven)
__device__ __forceinline__ void load_bq_asm(u32x4 (&bq)[5], const unsigned short* kybase) {
    const unsigned short* p = kybase + 1024;   // center; q*1024B-2048 fits 13-bit imm
    asm volatile("global_load_dwordx4 %0, %1, off offset:-2048" : "=v"(bq[0]) : "v"(p));
    asm volatile("global_load_dwordx4 %0, %1, off offset:-1024" : "=v"(bq[1]) : "v"(p));
    asm volatile("global_load_dwordx4 %0, %1, off"              : "=v"(bq[2]) : "v"(p));
    asm volatile("global_load_dwordx4 %0, %1, off offset:1024"  : "=v"(bq[3]) : "v"(p));
    asm volatile("global_load_dwordx4 %0, %1, off offset:2048"  : "=v"(bq[4]) : "v"(p));
}

// Burst of ds_read_b128 (R16-validated form); completion via lgkmcnt(0).
template<int NC>
__device__ __forceinline__ void ds_burst(u32x4 (&af)[NC], const unsigned short* rp) {
    unsigned a = (unsigned)(uintptr_t)rp;
    asm volatile("ds_read_b128 %0, %1 offset:0"   : "=v"(af[0]) : "v"(a));
    asm volatile("ds_read_b128 %0, %1 offset:32"  : "=v"(af[1]) : "v"(a));
    asm volatile("ds_read_b128 %0, %1 offset:64"  : "=v"(af[2]) : "v"(a));
    asm volatile("ds_read_b128 %0, %1 offset:96"  : "=v"(af[3]) : "v"(a));
    asm volatile("ds_read_b128 %0, %1 offset:128" : "=v"(af[4]) : "v"(a));
    asm volatile("ds_read_b128 %0, %1 offset:160" : "=v"(af[5]) : "v"(a));
    asm volatile("ds_read_b128 %0, %1 offset:192" : "=v"(af[6]) : "v"(a));
    asm volatile("ds_read_b128 %0, %1 offset:224" : "=v"(af[7]) : "v"(a));
    asm volatile("ds_read_b128 %0, %1 offset:256" : "=v"(af[8]) : "v"(a));
    if constexpr (NC > 9) {
        asm volatile("ds_read_b128 %0, %1 offset:288" : "=v"(af[9])  : "v"(a));
        asm volatile("ds_read_b128 %0, %1 offset:320" : "=v"(af[10]) : "v"(a));
    }
}

#define MFMA_(T,AF,Q) T = __builtin_amdgcn_mfma_f32_32x32x16_bf16( \
    __builtin_bit_cast(bf16x8, af[AF]), __builtin_bit_cast(bf16x8, bq[Q]), T, 0, 0, 0)

// ROUND-ROBIN accumulator order (the one change vs R16): q outer, tile inner.
// Same-acc MFMAs are NT apart (3-4 independent ops ~102-136cy) -> no C-in
// dependency stalls. All af chunks preloaded, so order is free.
template<int NT, int NC>
__device__ __forceinline__ void cluster(const u32x4 (&af)[NC], const u32x4 (&bq)[5],
                                        f32x16& A0, f32x16& A1, f32x16& A2, f32x16& A3)
{
#define RRQ(Q) \
    MFMA_(A0, 0+Q, Q); MFMA_(A1, 2+Q, Q); MFMA_(A2, 4+Q, Q); \
    if constexpr (NT == 4) { MFMA_(A3, 6+Q, Q); }
    RRQ(0) RRQ(1) RRQ(2) RRQ(3) RRQ(4)
#undef RRQ
}

#define SP1 __builtin_amdgcn_s_setprio(1)
#define SP0 __builtin_amdgcn_s_setprio(0)
// counted vmem wait + full DS drain + scheduler fence (rule #18)
#define VMWAIT_LG(N) do { asm volatile("s_waitcnt vmcnt(" #N ") lgkmcnt(0)" ::: "memory"); \
                          __builtin_amdgcn_sched_barrier(0); } while (0)

// Per phase: [burst NC ds_reads] [wait bq(ky)+DS] [pure-MFMA round-robin cluster]
template<int NT>
__device__ __forceinline__ void kloop_ws(
    const unsigned short* base,              // &s_band[(32wr+ln)*BSTR + 128xh + 8hi]
    const unsigned short* fb,                // tt frag base incl. lane offset
    f32x16& A0, f32x16& A1, f32x16& A2, f32x16& A3)
{
    constexpr int NC = (NT == 4) ? 11 : 9;
    u32x4 af[NC], bqA[5], bqB[5];
    load_bq_asm(bqA, fb);                    // ky 0
    load_bq_asm(bqB, fb + FRAGS);            // ky 1
    for (int ky = 0; ky < KK - 2; ky += 2) {
        ds_burst<NC>(af, base + ky*BSTR);
        VMWAIT_LG(5);                        // bqA(ky) done, bqB in flight; af done
        SP1; cluster<NT, NC>(af, bqA, A0, A1, A2, A3); SP0;
        load_bq_asm(bqA, fb + (size_t)(ky + 2)*FRAGS);
        ds_burst<NC>(af, base + (ky + 1)*BSTR);
        VMWAIT_LG(5);                        // bqB(ky+1) done, bqA in flight; af done
        SP1; cluster<NT, NC>(af, bqB, A0, A1, A2, A3); SP0;
        if (ky + 3 < KK)
            load_bq_asm(bqB, fb + (size_t)(ky + 3)*FRAGS);
    }
    ds_burst<NC>(af, base + (KK - 1)*BSTR);
    VMWAIT_LG(0);                            // ky = 36 (in bqA)
    SP1; cluster<NT, NC>(af, bqA, A0, A1, A2, A3); SP0;
}

// Fallback (tiny ws): unpipelined, plain loads.
__device__ __forceinline__ void load_bq_fb(u32x4 (&bq)[5], const unsigned short* s_w16,
                                           int ky, int hi, int ln) {
    #pragma unroll
    for (int q = 0; q < 5; ++q) {
        union { u32x4 v; unsigned short s[8]; } u;
        #pragma unroll
        for (int j = 0; j < 8; ++j) {
            int kx = 16*q + 8*hi + j - ln;
            u.s[j] = (kx >= 0 && kx < KK) ? s_w16[ky*40 + kx] : (unsigned short)0;
        }
        bq[q] = u.v;
    }
}

template<int NT, int NC>
__device__ __forceinline__ void kloop_fb(
    const unsigned short* base, const unsigned short* s_w16,
    int hi, int ln, f32x16& A0, f32x16& A1, f32x16& A2, f32x16& A3)
{
    u32x4 af[NC], bq[5];
    for (int ky = 0; ky < KK; ++ky) {
        load_bq_fb(bq, s_w16, ky, hi, ln);
        #pragma unroll
        for (int c = 0; c < NC; ++c)
            af[c] = *(const u32x4*)(base + ky*BSTR + 16*c);
        cluster<NT, NC>(af, bq, A0, A1, A2, A3);
    }
}

template<bool FROM_WS>
__global__ __launch_bounds__(256, 3) void optics_mfma(
    const float* __restrict__ batch,
    const float* __restrict__ psf,
    const unsigned short* __restrict__ tt,
    const int* __restrict__ params,
    const float* __restrict__ weights,
    float* __restrict__ out)
{
    __shared__ __align__(16) unsigned short s_band[BROWS*BSTR + 16]; // 52,832 B -> 3/CU
    __shared__ __align__(16) unsigned short s_w16[FROM_WS ? 8 : KK*40];

    const int tid = threadIdx.x;
    // XCD-chunked bijective swizzle (R13-proven)
    const int n = blockIdx.x;                 // 0..767
    const int item = (n & 7) * (NBLK / 8) + (n >> 3);
    const int plane = item >> 2;              // 0..191
    const int yband = item & 3;               // 0..3
    const int b = plane / CC, c = plane - b*CC;
    const int y0 = yband * BM;
    const int rows = (HH - y0 < BM) ? (HH - y0) : BM;   // 64,64,64,32
    const int brows = rows + KK - 1;
    const int p = params[b];

    // --- stage reflect-padded band, fp32 -> bf16 ---
    const float* src = batch + (size_t)plane * PLANE;
    for (int i = tid; i < brows*56; i += 256) {
        int r = i / 56, g = i - r*56;
        int gy = y0 + r - PP;
        gy = gy < 0 ? -gy : (gy >= HH ? 2*HH - 2 - gy : gy);
        float4 v = *(const float4*)&src[gy*WW + 4*g];
        unsigned int lo  = f2bf(v.x) | ((unsigned int)f2bf(v.y) << 16);
        unsigned int hi2 = f2bf(v.z) | ((unsigned int)f2bf(v.w) << 16);
        unsigned int* d = (unsigned int*)&s_band[r*BSTR + PP + 4*g];
        d[0] = lo; d[1] = hi2;
    }
    for (int i = tid; i < brows*40; i += 256) {
        int r = i / 40, e = i - r*40;
        int col = e < PP ? e : (224 + e);     // e=18..39 -> col 242..263
        unsigned short v = 0;
        if (col < 260) {
            int gy = y0 + r - PP;
            gy = gy < 0 ? -gy : (gy >= HH ? 2*HH - 2 - gy : gy);
            int gx = col - PP;
            gx = gx < 0 ? -gx : (gx >= WW ? 2*WW - 2 - gx : gx);
            v = f2bf(src[gy*WW + gx]);
        }
        s_band[r*BSTR + col] = v;
    }
    if (tid < 16) s_band[brows*BSTR + tid] = 0;   // guard (last-chunk overrun, B=0 there)
    if constexpr (!FROM_WS) {
        const float* ksrc = psf + (size_t)((p*5 + 2)*CC + c) * (KK*KK);
        for (int i = tid; i < KK*KK; i += 256) {
            int ky_ = i / KK, kx_ = i - ky_*KK;
            s_w16[ky_*40 + kx_] = f2bf(ksrc[i]);
        }
    }
    __syncthreads();     // drains all counters -> clean base for hand counting

    const int lane = tid & 63;
    const int wid  = tid >> 6;               // 0..3
    const int wr   = wid >> 1;               // stripe 0/1 (rows 0-31 / 32-63)
    const int xh   = wid & 1;                // x-half: tiles 0-3 / 4-6
    const int ln   = lane & 31;
    const int hi   = lane >> 5;
    const bool active = (wr == 0) || (rows > 32);

    if (active) {
        const unsigned short* base = &s_band[(32*wr + ln)*BSTR + 128*xh + 8*hi];

        f32x16 A0 = {0,0,0,0, 0,0,0,0, 0,0,0,0, 0,0,0,0};
        f32x16 A1 = A0, A2 = A0, A3 = A0;

        if constexpr (FROM_WS) {
            const unsigned short* fb = tt + (size_t)((p*CC + c)*KK)*FRAGS + hi*256 + ln*8;
            if (xh == 0) kloop_ws<4>(base, fb, A0, A1, A2, A3);
            else         kloop_ws<3>(base, fb, A0, A1, A2, A3);
        } else {
            if (xh == 0) kloop_fb<4, 11>(base, s_w16, hi, ln, A0, A1, A2, A3);
            else         kloop_fb<3, 9>(base, s_w16, hi, ln, A0, A1, A2, A3);
        }

        // --- epilogue: blend + store (m74 D layout) ---
        const float wt = weights[b];
        const float w1 = 1.0f - wt;
        float* dst = out + (size_t)plane * PLANE;
#define EPI(ACC, GT) { \
        _Pragma("unroll") \
        for (int r = 0; r < 16; ++r) { \
            const int rowL = (r & 3) + 8*(r >> 2) + 4*hi; \
            const int yo = y0 + 32*wr + rowL; \
            const int xo = 32*(GT) + ln; \
            const float orig = bf2f(s_band[(32*wr + rowL + PP)*BSTR + xo + PP]); \
            dst[yo*WW + xo] = w1*orig + wt*ACC[r]; \
        } }
        if (xh == 0) { EPI(A0, 0) EPI(A1, 1) EPI(A2, 2) EPI(A3, 3) }
        else         { EPI(A0, 4) EPI(A1, 5) EPI(A2, 6) }
#undef EPI
    }
}

__global__ void copy_targets(const int* __restrict__ t, float* __restrict__ out) {
    int i = threadIdx.x;
    if (i < BB) out[i] = (float)t[i];
}

extern "C" void kernel_launch(void* const* d_in, const int* in_sizes, int n_in,
                              void* d_out, int out_size, void* d_ws, size_t ws_size,
                              hipStream_t stream) {
    const float* batch   = (const float*)d_in[0];
    const int*   targets = (const int*)d_in[1];
    const float* psf     = (const float*)d_in[2];
    const int*   params  = (const int*)d_in[3];
    const float* weights = (const float*)d_in[4];
    float* out = (float*)d_out;
    unsigned short* tt = (unsigned short*)d_ws;

    if (ws_size >= TT_BYTES) {
        build_frags<<<NTT, 256, 0, stream>>>(psf, tt, targets,
                                             out + (size_t)BB*CC*PLANE);
        optics_mfma<true><<<NBLK, 256, 0, stream>>>(batch, psf, tt, params, weights, out);
    } else {
        optics_mfma<false><<<NBLK, 256, 0, stream>>>(batch, psf, tt, params, weights, out);
        copy_targets<<<1, 64, 0, stream>>>(targets, out + (size_t)BB*CC*PLANE);
    }
}

// Round 19
// 69.764 us; speedup vs baseline: 1.1398x; 1.0384x over previous
//
#include <hip/hip_runtime.h>

#define BB 64
#define CC 3
#define HH 224
#define WW 224
#define KK 37
#define PP 18
#define PLANE (HH*WW)

#define BM 64             // output rows per block (2 stripes); 224 = 3*64 + 32
#define BROWS 100         // BM + KK - 1
#define BSTR 264          // shorts per band row
#define FRAGS 2560        // shorts per (slab,ky): 5q x 2hi x 32ln x 8j
#define NTT (8*CC*KK)     // 888 fragment blocks
#define TT_BYTES ((size_t)NTT * FRAGS * sizeof(unsigned short))  // ~4.55 MB
#define NBLK 768          // 4 ybands x 192 planes = 3 per CU exactly

typedef __attribute__((ext_vector_type(8)))  __bf16 bf16x8;
typedef __attribute__((ext_vector_type(4)))  unsigned int u32x4;
typedef __attribute__((ext_vector_type(16))) float f32x16;

__device__ __forceinline__ unsigned short f2bf(float f) {
    unsigned int u = __float_as_uint(f);
    return (unsigned short)((u + 0x7FFFu + ((u >> 16) & 1u)) >> 16);   // RNE
}
__device__ __forceinline__ float bf2f(unsigned short h) {
    return __uint_as_float(((unsigned int)h) << 16);
}

// frag[s][q][hi][ln][j] = w[ky][16q+8hi+j - ln] (0 outside band); + targets
__global__ __launch_bounds__(256) void build_frags(
    const float* __restrict__ psf, unsigned short* __restrict__ tt,
    const int* __restrict__ targets, float* __restrict__ tout)
{
    const int s = blockIdx.x;                // (p*3+c)*37 + ky
    const int ky = s % KK;
    const int pc = s / KK;
    const int p = pc / CC, c = pc - (pc / CC) * CC;
    const float* wrow = psf + (size_t)(((p*5 + 2)*CC + c)*KK + ky) * KK;
    unsigned short* dst = tt + (size_t)s * FRAGS;
    for (int e = threadIdx.x; e < FRAGS; e += 256) {
        int j = e & 7, ln = (e >> 3) & 31, hi = (e >> 8) & 1, q = e >> 9;
        int kx = 16*q + 8*hi + j - ln;
        dst[e] = (kx >= 0 && kx < KK) ? f2bf(wrow[kx]) : (unsigned short)0;
    }
    if (s == 0 && threadIdx.x < BB) tout[threadIdx.x] = (float)targets[threadIdx.x];
}

// 5 asm global loads; completion via hand-counted vmcnt (R12/R13-proven)
__device__ __forceinline__ void load_bq_asm(u32x4 (&bq)[5], const unsigned short* kybase) {
    const unsigned short* p = kybase + 1024;   // center; q*1024B-2048 fits 13-bit imm
    asm volatile("global_load_dwordx4 %0, %1, off offset:-2048" : "=v"(bq[0]) : "v"(p));
    asm volatile("global_load_dwordx4 %0, %1, off offset:-1024" : "=v"(bq[1]) : "v"(p));
    asm volatile("global_load_dwordx4 %0, %1, off"              : "=v"(bq[2]) : "v"(p));
    asm volatile("global_load_dwordx4 %0, %1, off offset:1024"  : "=v"(bq[3]) : "v"(p));
    asm volatile("global_load_dwordx4 %0, %1, off offset:2048"  : "=v"(bq[4]) : "v"(p));
}

__device__ __forceinline__ void load_bq_fb(u32x4 (&bq)[5], const unsigned short* s_w16,
                                           int ky, int hi, int ln) {
    #pragma unroll
    for (int q = 0; q < 5; ++q) {
        union { u32x4 v; unsigned short s[8]; } u;
        #pragma unroll
        for (int j = 0; j < 8; ++j) {
            int kx = 16*q + 8*hi + j - ln;
            u.s[j] = (kx >= 0 && kx < KK) ? s_w16[ky*40 + kx] : (unsigned short)0;
        }
        bq[q] = u.v;
    }
}

#define MFMA_(T,Q) T = __builtin_amdgcn_mfma_f32_32x32x16_bf16( \
    __builtin_bit_cast(bf16x8, af), __builtin_bit_cast(bf16x8, bq[Q]), T, 0, 0, 0)

// R13's JIT interleave (best performer: compiler emits fine counted lgkmcnt).
template<int NT>
__device__ __forceinline__ void compute_ky(const unsigned short* rp, const u32x4 (&bq)[5],
                                           f32x16& A0, f32x16& A1, f32x16& A2, f32x16& A3)
{
    u32x4 af;
#define LDC(c) af = *(const u32x4*)(rp + 16*(c))
    LDC(0);  MFMA_(A0,0);
    LDC(1);  MFMA_(A0,1);
    LDC(2);  MFMA_(A0,2); MFMA_(A1,0);
    LDC(3);  MFMA_(A0,3); MFMA_(A1,1);
    LDC(4);  MFMA_(A0,4); MFMA_(A1,2); MFMA_(A2,0);
    LDC(5);  MFMA_(A1,3); MFMA_(A2,1);
    if constexpr (NT == 4) {
        LDC(6);  MFMA_(A1,4); MFMA_(A2,2); MFMA_(A3,0);
        LDC(7);  MFMA_(A2,3); MFMA_(A3,1);
        LDC(8);  MFMA_(A2,4); MFMA_(A3,2);
        LDC(9);  MFMA_(A3,3);
        LDC(10); MFMA_(A3,4);
    } else {
        LDC(6);  MFMA_(A1,4); MFMA_(A2,2);
        LDC(7);  MFMA_(A2,3);
        LDC(8);  MFMA_(A2,4);
    }
#undef LDC
}

#define SP1 __builtin_amdgcn_s_setprio(1)
#define SP0 __builtin_amdgcn_s_setprio(0)
#define VMWAIT(N) do { asm volatile("s_waitcnt vmcnt(" #N ")" ::: "memory"); \
                       __builtin_amdgcn_sched_barrier(0); } while (0)

// R13 pipeline + ky-ROTATION (start at `off`, wrap mod 37): de-convoys the 12
// waves/CU so one wave's LDS burst overlaps another's MFMA cluster. Order of
// accumulation is irrelevant; tt slab set per XCD unchanged (L2-resident).
template<int NT>
__device__ __forceinline__ void kloop_ws(
    const unsigned short* base, const unsigned short* fb, int off,
    f32x16& A0, f32x16& A1, f32x16& A2, f32x16& A3)
{
    u32x4 bqA[5], bqB[5];
    int kyA = off;
    int kyB = kyA + 1; if (kyB == KK) kyB = 0;
    load_bq_asm(bqA, fb + (size_t)kyA*FRAGS);
    load_bq_asm(bqB, fb + (size_t)kyB*FRAGS);
    for (int t = 0; t < KK - 1; t += 2) {
        VMWAIT(5);
        SP1; compute_ky<NT>(base + kyA*BSTR, bqA, A0, A1, A2, A3); SP0;
        int kyA2 = kyB + 1; if (kyA2 == KK) kyA2 = 0;
        if (t + 2 < KK)
            load_bq_asm(bqA, fb + (size_t)kyA2*FRAGS);
        VMWAIT(5);
        SP1; compute_ky<NT>(base + kyB*BSTR, bqB, A0, A1, A2, A3); SP0;
        int kyB2 = kyA2 + 1; if (kyB2 == KK) kyB2 = 0;
        if (t + 3 < KK)
            load_bq_asm(bqB, fb + (size_t)kyB2*FRAGS);
        kyA = kyA2; kyB = kyB2;
    }
    VMWAIT(0);
    SP1; compute_ky<NT>(base + kyA*BSTR, bqA, A0, A1, A2, A3); SP0;   // 37th
}

template<int NT>
__device__ __forceinline__ void kloop_fb(
    const unsigned short* base, const unsigned short* s_w16,
    int hi, int ln, f32x16& A0, f32x16& A1, f32x16& A2, f32x16& A3)
{
    u32x4 bq[5];
    for (int ky = 0; ky < KK; ++ky) {
        load_bq_fb(bq, s_w16, ky, hi, ln);
        compute_ky<NT>(base + ky*BSTR, bq, A0, A1, A2, A3);
    }
}

template<bool FROM_WS>
__global__ __launch_bounds__(256, 3) void optics_mfma(
    const float* __restrict__ batch,
    const float* __restrict__ psf,
    const unsigned short* __restrict__ tt,
    const int* __restrict__ params,
    const float* __restrict__ weights,
    float* __restrict__ out)
{
    __shared__ __align__(16) unsigned short s_band[BROWS*BSTR + 16]; // 52,832 B -> 3/CU
    __shared__ __align__(16) unsigned short s_w16[FROM_WS ? 8 : KK*40];

    const int tid = threadIdx.x;
    // XCD-chunked bijective swizzle (R13-proven)
    const int n = blockIdx.x;                 // 0..767
    const int item = (n & 7) * (NBLK / 8) + (n >> 3);
    const int plane = item >> 2;              // 0..191
    const int yband = item & 3;               // 0..3
    const int b = plane / CC, c = plane - b*CC;
    const int y0 = yband * BM;
    const int rows = (HH - y0 < BM) ? (HH - y0) : BM;   // 64,64,64,32
    const int brows = rows + KK - 1;
    const int p = params[b];

    // --- stage reflect-padded band, fp32 -> bf16 ---
    const float* src = batch + (size_t)plane * PLANE;
    for (int i = tid; i < brows*56; i += 256) {
        int r = i / 56, g = i - r*56;
        int gy = y0 + r - PP;
        gy = gy < 0 ? -gy : (gy >= HH ? 2*HH - 2 - gy : gy);
        float4 v = *(const float4*)&src[gy*WW + 4*g];
        unsigned int lo  = f2bf(v.x) | ((unsigned int)f2bf(v.y) << 16);
        unsigned int hi2 = f2bf(v.z) | ((unsigned int)f2bf(v.w) << 16);
        unsigned int* d = (unsigned int*)&s_band[r*BSTR + PP + 4*g];
        d[0] = lo; d[1] = hi2;
    }
    for (int i = tid; i < brows*40; i += 256) {
        int r = i / 40, e = i - r*40;
        int col = e < PP ? e : (224 + e);     // e=18..39 -> col 242..263
        unsigned short v = 0;
        if (col < 260) {
            int gy = y0 + r - PP;
            gy = gy < 0 ? -gy : (gy >= HH ? 2*HH - 2 - gy : gy);
            int gx = col - PP;
            gx = gx < 0 ? -gx : (gx >= WW ? 2*WW - 2 - gx : gx);
            v = f2bf(src[gy*WW + gx]);
        }
        s_band[r*BSTR + col] = v;
    }
    if (tid < 16) s_band[brows*BSTR + tid] = 0;   // guard (last-chunk overrun, B=0 there)
    if constexpr (!FROM_WS) {
        const float* ksrc = psf + (size_t)((p*5 + 2)*CC + c) * (KK*KK);
        for (int i = tid; i < KK*KK; i += 256) {
            int ky_ = i / KK, kx_ = i - ky_*KK;
            s_w16[ky_*40 + kx_] = f2bf(ksrc[i]);
        }
    }
    __syncthreads();     // drains vmcnt -> clean counter base for kloop_ws

    const int lane = tid & 63;
    const int wid  = tid >> 6;               // 0..3
    const int wr   = wid >> 1;               // stripe 0/1 (rows 0-31 / 32-63)
    const int xh   = wid & 1;                // x-half: tiles 0-3 / 4-6
    const int ln   = lane & 31;
    const int hi   = lane >> 5;
    const bool active = (wr == 0) || (rows > 32);
    // de-convoy offset: distinct per wave AND per co-resident block (same-SIMD
    // waves share wid but differ in yband)
    const int off = (9*wid + 19*yband) % KK;

    if (active) {
        const unsigned short* base = &s_band[(32*wr + ln)*BSTR + 128*xh + 8*hi];

        f32x16 A0 = {0,0,0,0, 0,0,0,0, 0,0,0,0, 0,0,0,0};
        f32x16 A1 = A0, A2 = A0, A3 = A0;

        if constexpr (FROM_WS) {
            const unsigned short* fb = tt + (size_t)((p*CC + c)*KK)*FRAGS + hi*256 + ln*8;
            if (xh == 0) kloop_ws<4>(base, fb, off, A0, A1, A2, A3);
            else         kloop_ws<3>(base, fb, off, A0, A1, A2, A3);
        } else {
            if (xh == 0) kloop_fb<4>(base, s_w16, hi, ln, A0, A1, A2, A3);
            else         kloop_fb<3>(base, s_w16, hi, ln, A0, A1, A2, A3);
        }

        // --- epilogue: blend + store (m74 D layout) ---
        const float wt = weights[b];
        const float w1 = 1.0f - wt;
        float* dst = out + (size_t)plane * PLANE;
#define EPI(ACC, GT) { \
        _Pragma("unroll") \
        for (int r = 0; r < 16; ++r) { \
            const int rowL = (r & 3) + 8*(r >> 2) + 4*hi; \
            const int yo = y0 + 32*wr + rowL; \
            const int xo = 32*(GT) + ln; \
            const float orig = bf2f(s_band[(32*wr + rowL + PP)*BSTR + xo + PP]); \
            dst[yo*WW + xo] = w1*orig + wt*ACC[r]; \
        } }
        if (xh == 0) { EPI(A0, 0) EPI(A1, 1) EPI(A2, 2) EPI(A3, 3) }
        else         { EPI(A0, 4) EPI(A1, 5) EPI(A2, 6) }
#undef EPI
    }
}

__global__ void copy_targets(const int* __restrict__ t, float* __restrict__ out) {
    int i = threadIdx.x;
    if (i < BB) out[i] = (float)t[i];
}

extern "C" void kernel_launch(void* const* d_in, const int* in_sizes, int n_in,
                              void* d_out, int out_size, void* d_ws, size_t ws_size,
                              hipStream_t stream) {
    const float* batch   = (const float*)d_in[0];
    const int*   targets = (const int*)d_in[1];
    const float* psf     = (const float*)d_in[2];
    const int*   params  = (const int*)d_in[3];
    const float* weights = (const float*)d_in[4];
    float* out = (float*)d_out;
    unsigned short* tt = (unsigned short*)d_ws;

    if (ws_size >= TT_BYTES) {
        build_frags<<<NTT, 256, 0, stream>>>(psf, tt, targets,
                                             out + (size_t)BB*CC*PLANE);
        optics_mfma<true><<<NBLK, 256, 0, stream>>>(batch, psf, tt, params, weights, out);
    } else {
        optics_mfma<false><<<NBLK, 256, 0, stream>>>(batch, psf, tt, params, weights, out);
        copy_targets<<<1, 64, 0, stream>>>(targets, out + (size_t)BB*CC*PLANE);
    }
}

// Round 20
// 68.194 us; speedup vs baseline: 1.1661x; 1.0230x over previous
//
#include <hip/hip_runtime.h>

#define BB 64
#define CC 3
#define HH 224
#define WW 224
#define KK 37
#define PP 18
#define PLANE (HH*WW)

#define BM 64             // output rows per block (2 stripes); 224 = 3*64 + 32
#define BROWS 100         // BM + KK - 1
#define BSTR 264          // shorts per band row
#define FRAGS 2560        // shorts per (slab,ky): 5q x 2hi x 32ln x 8j
#define NTT (8*CC*KK)     // 888 fragment blocks
#define TT_BYTES ((size_t)NTT * FRAGS * sizeof(unsigned short))  // ~4.55 MB
#define NBLK 768          // 4 ybands x 192 planes = 3 per CU exactly

typedef __attribute__((ext_vector_type(8)))  __bf16 bf16x8;
typedef __attribute__((ext_vector_type(4)))  unsigned int u32x4;
typedef __attribute__((ext_vector_type(16))) float f32x16;

__device__ __forceinline__ unsigned short f2bf(float f) {
    unsigned int u = __float_as_uint(f);
    return (unsigned short)((u + 0x7FFFu + ((u >> 16) & 1u)) >> 16);   // RNE
}
__device__ __forceinline__ float bf2f(unsigned short h) {
    return __uint_as_float(((unsigned int)h) << 16);
}

// frag[s][q][hi][ln][j] = w[ky][16q+8hi+j - ln] (0 outside band); + targets
__global__ __launch_bounds__(256) void build_frags(
    const float* __restrict__ psf, unsigned short* __restrict__ tt,
    const int* __restrict__ targets, float* __restrict__ tout)
{
    const int s = blockIdx.x;                // (p*3+c)*37 + ky
    const int ky = s % KK;
    const int pc = s / KK;
    const int p = pc / CC, c = pc - (pc / CC) * CC;
    const float* wrow = psf + (size_t)(((p*5 + 2)*CC + c)*KK + ky) * KK;
    unsigned short* dst = tt + (size_t)s * FRAGS;
    for (int e = threadIdx.x; e < FRAGS; e += 256) {
        int j = e & 7, ln = (e >> 3) & 31, hi = (e >> 8) & 1, q = e >> 9;
        int kx = 16*q + 8*hi + j - ln;
        dst[e] = (kx >= 0 && kx < KK) ? f2bf(wrow[kx]) : (unsigned short)0;
    }
    if (s == 0 && threadIdx.x < BB) tout[threadIdx.x] = (float)targets[threadIdx.x];
}

// 5 asm global loads: compiler cannot sink/merge; completion hand-counted (R12-proven)
__device__ __forceinline__ void load_bq_asm(u32x4 (&bq)[5], const unsigned short* kybase) {
    const unsigned short* p = kybase + 1024;   // center; q*1024B-2048 fits 13-bit imm
    asm volatile("global_load_dwordx4 %0, %1, off offset:-2048" : "=v"(bq[0]) : "v"(p));
    asm volatile("global_load_dwordx4 %0, %1, off offset:-1024" : "=v"(bq[1]) : "v"(p));
    asm volatile("global_load_dwordx4 %0, %1, off"              : "=v"(bq[2]) : "v"(p));
    asm volatile("global_load_dwordx4 %0, %1, off offset:1024"  : "=v"(bq[3]) : "v"(p));
    asm volatile("global_load_dwordx4 %0, %1, off offset:2048"  : "=v"(bq[4]) : "v"(p));
}

__device__ __forceinline__ void load_bq_fb(u32x4 (&bq)[5], const unsigned short* s_w16,
                                           int ky, int hi, int ln) {
    #pragma unroll
    for (int q = 0; q < 5; ++q) {
        union { u32x4 v; unsigned short s[8]; } u;
        #pragma unroll
        for (int j = 0; j < 8; ++j) {
            int kx = 16*q + 8*hi + j - ln;
            u.s[j] = (kx >= 0 && kx < KK) ? s_w16[ky*40 + kx] : (unsigned short)0;
        }
        bq[q] = u.v;
    }
}

#define MFMA_(T,Q) T = __builtin_amdgcn_mfma_f32_32x32x16_bf16( \
    __builtin_bit_cast(bf16x8, af), __builtin_bit_cast(bf16x8, bq[Q]), T, 0, 0, 0)

// NT=4: tiles at +0,32,64,96 (chunks 0-10); NT=3: +0,32,64 (chunks 0-8).
// Tile t uses chunks 2t..2t+4 with bq[c-2t]. af chunks JIT from LDS (the
// compiler emits fine-grained counted lgkmcnt here - measured best form).
template<int NT>
__device__ __forceinline__ void compute_ky(const unsigned short* rp, const u32x4 (&bq)[5],
                                           f32x16& A0, f32x16& A1, f32x16& A2, f32x16& A3)
{
    u32x4 af;
#define LDC(c) af = *(const u32x4*)(rp + 16*(c))
    LDC(0);  MFMA_(A0,0);
    LDC(1);  MFMA_(A0,1);
    LDC(2);  MFMA_(A0,2); MFMA_(A1,0);
    LDC(3);  MFMA_(A0,3); MFMA_(A1,1);
    LDC(4);  MFMA_(A0,4); MFMA_(A1,2); MFMA_(A2,0);
    LDC(5);  MFMA_(A1,3); MFMA_(A2,1);
    if constexpr (NT == 4) {
        LDC(6);  MFMA_(A1,4); MFMA_(A2,2); MFMA_(A3,0);
        LDC(7);  MFMA_(A2,3); MFMA_(A3,1);
        LDC(8);  MFMA_(A2,4); MFMA_(A3,2);
        LDC(9);  MFMA_(A3,3);
        LDC(10); MFMA_(A3,4);
    } else {
        LDC(6);  MFMA_(A1,4); MFMA_(A2,2);
        LDC(7);  MFMA_(A2,3);
        LDC(8);  MFMA_(A2,4);
    }
#undef LDC
}

#define SP1 __builtin_amdgcn_s_setprio(1)
#define SP0 __builtin_amdgcn_s_setprio(0)
#define VMWAIT(N) do { asm volatile("s_waitcnt vmcnt(" #N ")" ::: "memory"); \
                       __builtin_amdgcn_sched_barrier(0); } while (0)

// 2-deep asm bq pipeline, 10 loads in flight, counted vmcnt(5).
template<int NT>
__device__ __forceinline__ void kloop_ws(
    const unsigned short* base, const unsigned short* fb,
    f32x16& A0, f32x16& A1, f32x16& A2, f32x16& A3)
{
    u32x4 bqA[5], bqB[5];
    load_bq_asm(bqA, fb);                        // ky 0
    load_bq_asm(bqB, fb + FRAGS);                // ky 1
    for (int ky = 0; ky < KK - 2; ky += 2) {
        VMWAIT(5);
        SP1; compute_ky<NT>(base + ky*BSTR, bqA, A0, A1, A2, A3); SP0;
        load_bq_asm(bqA, fb + (size_t)(ky + 2)*FRAGS);
        VMWAIT(5);
        SP1; compute_ky<NT>(base + (ky + 1)*BSTR, bqB, A0, A1, A2, A3); SP0;
        if (ky + 3 < KK)
            load_bq_asm(bqB, fb + (size_t)(ky + 3)*FRAGS);
    }
    VMWAIT(0);
    SP1; compute_ky<NT>(base + (KK - 1)*BSTR, bqA, A0, A1, A2, A3); SP0;
}

template<int NT>
__device__ __forceinline__ void kloop_fb(
    const unsigned short* base, const unsigned short* s_w16,
    int hi, int ln, f32x16& A0, f32x16& A1, f32x16& A2, f32x16& A3)
{
    u32x4 bq[5];
    for (int ky = 0; ky < KK; ++ky) {
        load_bq_fb(bq, s_w16, ky, hi, ln);
        compute_ky<NT>(base + ky*BSTR, bq, A0, A1, A2, A3);
    }
}

template<bool FROM_WS>
__global__ __launch_bounds__(256, 3) void optics_mfma(
    const float* __restrict__ batch,
    const float* __restrict__ psf,
    const unsigned short* __restrict__ tt,
    const int* __restrict__ params,
    const float* __restrict__ weights,
    float* __restrict__ out)
{
    __shared__ __align__(16) unsigned short s_band[BROWS*BSTR + 16]; // 52,832 B -> 3/CU
    __shared__ __align__(16) unsigned short s_w16[FROM_WS ? 8 : KK*40];

    const int tid = threadIdx.x;
    // XCD-chunked bijective swizzle: XCD j gets items [96j, 96j+96) = 24 planes,
    // so each XCD's L2 holds a few hot 185KB tt slab streams (FETCH -> pure I/O).
    const int n = blockIdx.x;                 // 0..767
    const int item = (n & 7) * (NBLK / 8) + (n >> 3);
    const int plane = item >> 2;              // 0..191
    const int yband = item & 3;               // 0..3
    const int b = plane / CC, c = plane - b*CC;
    const int y0 = yband * BM;
    const int rows = (HH - y0 < BM) ? (HH - y0) : BM;   // 64,64,64,32
    const int brows = rows + KK - 1;
    const int p = params[b];

    // --- stage reflect-padded band, fp32 -> bf16 ---
    const float* src = batch + (size_t)plane * PLANE;
    // interior: gx 0..223 as 56 aligned float4 groups -> cols 18..241
    for (int i = tid; i < brows*56; i += 256) {
        int r = i / 56, g = i - r*56;
        int gy = y0 + r - PP;
        gy = gy < 0 ? -gy : (gy >= HH ? 2*HH - 2 - gy : gy);
        float4 v = *(const float4*)&src[gy*WW + 4*g];
        unsigned int lo  = f2bf(v.x) | ((unsigned int)f2bf(v.y) << 16);
        unsigned int hi2 = f2bf(v.z) | ((unsigned int)f2bf(v.w) << 16);
        unsigned int* d = (unsigned int*)&s_band[r*BSTR + PP + 4*g];
        d[0] = lo; d[1] = hi2;
    }
    // edges: cols 0..17 (left reflect), 242..259 (right reflect), 260..263 (zero)
    for (int i = tid; i < brows*40; i += 256) {
        int r = i / 40, e = i - r*40;
        int col = e < PP ? e : (224 + e);     // e=18..39 -> col 242..263
        unsigned short v = 0;
        if (col < 260) {
            int gy = y0 + r - PP;
            gy = gy < 0 ? -gy : (gy >= HH ? 2*HH - 2 - gy : gy);
            int gx = col - PP;
            gx = gx < 0 ? -gx : (gx >= WW ? 2*WW - 2 - gx : gx);
            v = f2bf(src[gy*WW + gx]);
        }
        s_band[r*BSTR + col] = v;
    }
    if (tid < 16) s_band[brows*BSTR + tid] = 0;   // guard (last-chunk overrun, B=0 there)
    if constexpr (!FROM_WS) {
        const float* ksrc = psf + (size_t)((p*5 + 2)*CC + c) * (KK*KK);
        for (int i = tid; i < KK*KK; i += 256) {
            int ky_ = i / KK, kx_ = i - ky_*KK;
            s_w16[ky_*40 + kx_] = f2bf(ksrc[i]);
        }
    }
    __syncthreads();     // drains vmcnt -> clean counter base for kloop_ws

    const int lane = tid & 63;
    const int wid  = tid >> 6;               // 0..3
    const int wr   = wid >> 1;               // stripe 0/1 (rows 0-31 / 32-63)
    const int xh   = wid & 1;                // x-half: tiles 0-3 / 4-6
    const int ln   = lane & 31;
    const int hi   = lane >> 5;
    const bool active = (wr == 0) || (rows > 32);

    if (active) {
        const unsigned short* base = &s_band[(32*wr + ln)*BSTR + 128*xh + 8*hi];

        f32x16 A0 = {0,0,0,0, 0,0,0,0, 0,0,0,0, 0,0,0,0};
        f32x16 A1 = A0, A2 = A0, A3 = A0;

        if constexpr (FROM_WS) {
            const unsigned short* fb = tt + (size_t)((p*CC + c)*KK)*FRAGS + hi*256 + ln*8;
            if (xh == 0) kloop_ws<4>(base, fb, A0, A1, A2, A3);
            else         kloop_ws<3>(base, fb, A0, A1, A2, A3);
        } else {
            if (xh == 0) kloop_fb<4>(base, s_w16, hi, ln, A0, A1, A2, A3);
            else         kloop_fb<3>(base, s_w16, hi, ln, A0, A1, A2, A3);
        }

        // --- epilogue: blend + store (m74 D layout) ---
        const float wt = weights[b];
        const float w1 = 1.0f - wt;
        float* dst = out + (size_t)plane * PLANE;
#define EPI(ACC, GT) { \
        _Pragma("unroll") \
        for (int r = 0; r < 16; ++r) { \
            const int rowL = (r & 3) + 8*(r >> 2) + 4*hi; \
            const int yo = y0 + 32*wr + rowL; \
            const int xo = 32*(GT) + ln; \
            const float orig = bf2f(s_band[(32*wr + rowL + PP)*BSTR + xo + PP]); \
            dst[yo*WW + xo] = w1*orig + wt*ACC[r]; \
        } }
        if (xh == 0) { EPI(A0, 0) EPI(A1, 1) EPI(A2, 2) EPI(A3, 3) }
        else         { EPI(A0, 4) EPI(A1, 5) EPI(A2, 6) }
#undef EPI
    }
}

__global__ void copy_targets(const int* __restrict__ t, float* __restrict__ out) {
    int i = threadIdx.x;
    if (i < BB) out[i] = (float)t[i];
}

extern "C" void kernel_launch(void* const* d_in, const int* in_sizes, int n_in,
                              void* d_out, int out_size, void* d_ws, size_t ws_size,
                              hipStream_t stream) {
    const float* batch   = (const float*)d_in[0];
    const int*   targets = (const int*)d_in[1];
    const float* psf     = (const float*)d_in[2];
    const int*   params  = (const int*)d_in[3];
    const float* weights = (const float*)d_in[4];
    float* out = (float*)d_out;
    unsigned short* tt = (unsigned short*)d_ws;

    if (ws_size >= TT_BYTES) {
        build_frags<<<NTT, 256, 0, stream>>>(psf, tt, targets,
                                             out + (size_t)BB*CC*PLANE);
        optics_mfma<true><<<NBLK, 256, 0, stream>>>(batch, psf, tt, params, weights, out);
    } else {
        optics_mfma<false><<<NBLK, 256, 0, stream>>>(batch, psf, tt, params, weights, out);
        copy_targets<<<1, 64, 0, stream>>>(targets, out + (size_t)BB*CC*PLANE);
    }
}